// Round 4
// baseline (372.696 us; speedup 1.0000x reference)
//
#include <hip/hip_runtime.h>

#define NTOK 4096
#define NEXP 8
#define MAXTILES 104

typedef __attribute__((ext_vector_type(8))) short short8;
typedef __attribute__((ext_vector_type(4))) float f32x4;
typedef __attribute__((ext_vector_type(4))) unsigned int uint4v;
typedef __attribute__((ext_vector_type(2))) unsigned int uint2v;

__device__ __forceinline__ unsigned short f2bf(float f) {
  union { float f; unsigned u; } v; v.f = f;
  unsigned u = v.u;
  return (unsigned short)((u + 0x7FFFu + ((u >> 16) & 1u)) >> 16);
}

__device__ __forceinline__ void gll16(const void* g, void* l) {
  __builtin_amdgcn_global_load_lds((const __attribute__((address_space(1))) void*)g,
                                   (__attribute__((address_space(3))) void*)l, 16, 0, 0);
}

// derive this block's tile from counts[] (replaces build_k's tiles/ebase tables)
__device__ __forceinline__ bool tile_lookup(const int* __restrict__ counts, int y,
                                            int& e, int& m0, int& n_e, int& hb) {
  int base = 0, acc = 0;
#pragma unroll
  for (int ee = 0; ee < NEXP; ++ee) {
    int c = counts[ee];
    int nt = (c + 127) >> 7;
    if (y < acc + nt) { e = ee; m0 = (y - acc) << 7; n_e = c; hb = base; return true; }
    acc += nt; base += nt << 7;
  }
  int ys = y - acc;
  if (ys < 32) { e = NEXP; m0 = ys << 7; n_e = NTOK; hb = base; return true; }
  return false;
}

// shared 64x64 fp32->bf16 transpose tile body (proven: 0 bank conflicts)
__device__ __forceinline__ void transpose_tile(const float* __restrict__ S,
                                               unsigned short* __restrict__ Dp,
                                               int r0, int c0, int t,
                                               unsigned short (*tile)[65]) {
  int r = t >> 2, cb = (t & 3) * 16;
  const float* sp = S + (size_t)(r0 + r) * 1024 + c0 + cb;
  f32x4 v0 = ((const f32x4*)sp)[0], v1 = ((const f32x4*)sp)[1];
  f32x4 v2 = ((const f32x4*)sp)[2], v3 = ((const f32x4*)sp)[3];
#pragma unroll
  for (int j = 0; j < 4; ++j) {
    tile[r][cb + j] = f2bf(v0[j]);
    tile[r][cb + 4 + j] = f2bf(v1[j]);
    tile[r][cb + 8 + j] = f2bf(v2[j]);
    tile[r][cb + 12 + j] = f2bf(v3[j]);
  }
  __syncthreads();
  unsigned short* dp = Dp + (size_t)(c0 + r) * 1024 + r0 + cb;
  uint4v o0, o1;
#pragma unroll
  for (int j = 0; j < 4; ++j) {
    o0[j] = (unsigned)tile[cb + 2 * j][r] | ((unsigned)tile[cb + 2 * j + 1][r] << 16);
    o1[j] = (unsigned)tile[cb + 8 + 2 * j][r] | ((unsigned)tile[cb + 9 + 2 * j][r] << 16);
  }
  ((uint4v*)dp)[0] = o0;
  ((uint4v*)dp)[1] = o1;
}

// ---- prep: blocks [0,4608) = w1/w3/sw1/sw3 transpose; [4608,5632) = router ----
// router now atomically appends to tlist/wlist (counts pre-zeroed by memset) — no build_k
__global__ __launch_bounds__(256) void prep_k(
    const float* __restrict__ w1, const float* __restrict__ w3,
    const float* __restrict__ sw1, const float* __restrict__ sw3,
    unsigned short* __restrict__ dst /* w1T base */,
    const float* __restrict__ x, const float* __restrict__ wr, unsigned short* __restrict__ xb,
    int* __restrict__ counts, int* __restrict__ tlist, float* __restrict__ wlist,
    float* __restrict__ probs, float* __restrict__ lsebuf) {
  __shared__ unsigned short tile[64][65];
  int b = blockIdx.x;
  if (b < 4608) {
    int z = b >> 8, rem = b & 255;
    const float* S;
    unsigned short* Dp;
    if (z < 8) { S = w1 + (size_t)z * 1048576; Dp = dst + (size_t)z * 1048576; }
    else if (z < 16) { S = w3 + (size_t)(z - 8) * 1048576; Dp = dst + (size_t)z * 1048576; }
    else if (z == 16) { S = sw1; Dp = dst + (size_t)24 * 1048576; }
    else { S = sw3; Dp = dst + (size_t)25 * 1048576; }
    transpose_tile(S, Dp, (rem >> 4) * 64, (rem & 15) * 64, threadIdx.x, tile);
  } else {
    int t = threadIdx.x, lane = t & 63, wv = t >> 6;
    int tok = (b - 4608) * 4 + wv;
    const f32x4* x4 = (const f32x4*)(x + (size_t)tok * 1024);
    f32x4 xv[4];
#pragma unroll
    for (int j = 0; j < 4; ++j) xv[j] = x4[j * 64 + lane];

    unsigned short* xo = xb + (size_t)tok * 1024;
#pragma unroll
    for (int j = 0; j < 4; ++j) {
      uint2v o;
      o[0] = (unsigned)f2bf(xv[j][0]) | ((unsigned)f2bf(xv[j][1]) << 16);
      o[1] = (unsigned)f2bf(xv[j][2]) | ((unsigned)f2bf(xv[j][3]) << 16);
      *(uint2v*)(xo + j * 256 + lane * 4) = o;
    }

    float acc[NEXP];
#pragma unroll
    for (int e = 0; e < NEXP; ++e) acc[e] = 0.f;
#pragma unroll
    for (int j = 0; j < 4; ++j) {
      int base = j * 256 + lane * 4;
#pragma unroll
      for (int c = 0; c < 4; ++c) {
        float xf = xv[j][c];
        const f32x4* wp = (const f32x4*)(wr + (size_t)(base + c) * NEXP);
        f32x4 q0 = wp[0], q1 = wp[1];
#pragma unroll
        for (int e = 0; e < 4; ++e) { acc[e] += xf * q0[e]; acc[4 + e] += xf * q1[e]; }
      }
    }
#pragma unroll
    for (int off = 32; off > 0; off >>= 1) {
#pragma unroll
      for (int e = 0; e < NEXP; ++e) acc[e] += __shfl_xor(acc[e], off);
    }

    float mx = acc[0];
#pragma unroll
    for (int e = 1; e < NEXP; ++e) mx = fmaxf(mx, acc[e]);
    float s = 0.f;
#pragma unroll
    for (int e = 0; e < NEXP; ++e) s += __expf(acc[e] - mx);
    float inv = 1.f / s;

    if (lane < NEXP) probs[(size_t)tok * NEXP + lane] = __expf(acc[lane] - mx) * inv;
    if (lane == 0) {
      int i0 = 0; float v0 = acc[0];
#pragma unroll
      for (int e = 1; e < NEXP; ++e) if (acc[e] > v0) { v0 = acc[e]; i0 = e; }
      int i1 = -1; float v1 = -3.4e38f;
#pragma unroll
      for (int e = 0; e < NEXP; ++e) if (e != i0 && acc[e] > v1) { v1 = acc[e]; i1 = e; }
      int p0 = atomicAdd(&counts[i0], 1);
      tlist[i0 * NTOK + p0] = tok;
      wlist[i0 * NTOK + p0] = __expf(v0 - mx) * inv;
      int p1 = atomicAdd(&counts[i1], 1);
      tlist[i1 * NTOK + p1] = tok | (1 << 16);
      wlist[i1 * NTOK + p1] = __expf(v1 - mx) * inv;
      lsebuf[tok] = mx + __logf(s);
    }
  }
}

// ---- GEMM1: y<MAXTILES: 128x64 dual-B SwiGLU tiles; y>=MAXTILES: w2/sw2 transpose ----
// launch_bounds (256,3): proven optimum — 4 blocks/CU thrashes L2 (R2: FETCH 117->205MB, 2x dur)
__global__ __launch_bounds__(256, 3) void gemm1_k(
    const unsigned short* __restrict__ xb,
    const unsigned short* __restrict__ w1T, const unsigned short* __restrict__ w3T,
    const unsigned short* __restrict__ sw1T, const unsigned short* __restrict__ sw3T,
    unsigned short* __restrict__ hout,
    const int* __restrict__ tlist, const int* __restrict__ counts,
    const float* __restrict__ w2, const float* __restrict__ sw2,
    unsigned short* __restrict__ wTbase /* = w1T; w2T at +16M, sw2T at +26M */) {
  __shared__ unsigned short As[128 * 64], Bs1[64 * 64], Bs3[64 * 64];
  const int tid = threadIdx.x;

  if (blockIdx.y >= MAXTILES) {
    // ---- w2/sw2 transpose: 9 slices x 256 tiles ----
    int tb = (blockIdx.y - MAXTILES) * 16 + blockIdx.x;  // 0..2303
    int z = tb >> 8, rem = tb & 255;
    const float* S = (z < 8) ? w2 + (size_t)z * 1048576 : sw2;
    unsigned short* Dp = (z < 8) ? wTbase + (size_t)(16 + z) * 1048576
                                 : wTbase + (size_t)26 * 1048576;
    transpose_tile(S, Dp, (rem >> 4) * 64, (rem & 15) * 64, tid,
                   (unsigned short (*)[65])As);
    return;
  }

  int e, m0, n_e, hb;
  if (!tile_lookup(counts, blockIdx.y, e, m0, n_e, hb)) return;
  const int n0 = blockIdx.x * 64;
  const bool sh = (e == NEXP);
  const unsigned short* B1p = sh ? sw1T : w1T + (size_t)e * 1048576;
  const unsigned short* B3p = sh ? sw3T : w3T + (size_t)e * 1048576;
  const int* listp = tlist + e * NTOK;

  const int lane = tid & 63, wv = tid >> 6;
  const int wrw = wv >> 1, wc = wv & 1, l16 = lane & 15, lq = lane >> 4;

  const unsigned short* ga[4];
#pragma unroll
  for (int i = 0; i < 4; ++i) {
    int c = tid + i * 256;
    int r = c >> 3, ks = (c & 7) ^ (r & 7);
    int ar = m0 + r;
    int rowA = sh ? ar : (ar < n_e ? (listp[ar] & 0xFFFF) : 0);
    ga[i] = xb + (size_t)rowA * 1024 + ks * 8;
  }
  const unsigned short* gb[2];
  const unsigned short* gc[2];
#pragma unroll
  for (int i = 0; i < 2; ++i) {
    int c = tid + i * 256;
    int r = c >> 3, ks = (c & 7) ^ (r & 7);
    gb[i] = B1p + (size_t)(n0 + r) * 1024 + ks * 8;
    gc[i] = B3p + (size_t)(n0 + r) * 1024 + ks * 8;
  }
  unsigned short* lA[4];
#pragma unroll
  for (int i = 0; i < 4; ++i) lA[i] = As + i * 2048 + wv * 512;
  unsigned short* lB[2] = {Bs1 + wv * 512, Bs1 + 2048 + wv * 512};
  unsigned short* lC[2] = {Bs3 + wv * 512, Bs3 + 2048 + wv * 512};

  f32x4 accg[4][2], accu[4][2];
#pragma unroll
  for (int mi = 0; mi < 4; ++mi)
#pragma unroll
    for (int ni = 0; ni < 2; ++ni)
#pragma unroll
      for (int r = 0; r < 4; ++r) { accg[mi][ni][r] = 0.f; accu[mi][ni][r] = 0.f; }

  for (int k0 = 0; k0 < 1024; k0 += 64) {
#pragma unroll
    for (int i = 0; i < 4; ++i) { gll16(ga[i], lA[i]); ga[i] += 64; }
#pragma unroll
    for (int i = 0; i < 2; ++i) { gll16(gb[i], lB[i]); gb[i] += 64; gll16(gc[i], lC[i]); gc[i] += 64; }
    __syncthreads();
#pragma unroll
    for (int kh = 0; kh < 2; ++kh) {
      short8 af[4], b1f[2], b3f[2];
#pragma unroll
      for (int mi = 0; mi < 4; ++mi) {
        int R = wrw * 64 + mi * 16 + l16;
        int s = (kh * 4 + lq) ^ (R & 7);
        af[mi] = *(const short8*)&As[R * 64 + s * 8];
      }
#pragma unroll
      for (int ni = 0; ni < 2; ++ni) {
        int R = wc * 32 + ni * 16 + l16;
        int s = (kh * 4 + lq) ^ (R & 7);
        b1f[ni] = *(const short8*)&Bs1[R * 64 + s * 8];
        b3f[ni] = *(const short8*)&Bs3[R * 64 + s * 8];
      }
#pragma unroll
      for (int mi = 0; mi < 4; ++mi)
#pragma unroll
        for (int ni = 0; ni < 2; ++ni) {
          accg[mi][ni] = __builtin_amdgcn_mfma_f32_16x16x32_bf16(af[mi], b1f[ni], accg[mi][ni], 0, 0, 0);
          accu[mi][ni] = __builtin_amdgcn_mfma_f32_16x16x32_bf16(af[mi], b3f[ni], accu[mi][ni], 0, 0, 0);
        }
    }
    __syncthreads();
  }

#pragma unroll
  for (int mi = 0; mi < 4; ++mi)
#pragma unroll
    for (int ni = 0; ni < 2; ++ni) {
      int col = n0 + wc * 32 + ni * 16 + l16;
#pragma unroll
      for (int r = 0; r < 4; ++r) {
        int row = m0 + wrw * 64 + mi * 16 + lq * 4 + r;
        float g = accg[mi][ni][r], u = accu[mi][ni][r];
        float h = g / (1.f + __expf(-g)) * u;
        hout[(size_t)(hb + row) * 1024 + col] = (row < n_e) ? f2bf(h) : (unsigned short)0;
      }
    }
}

// ---- GEMM2: 128x64 tile, BK=64; expert tiles -> ybuf[k] slices, shared tiles -> out ----
__global__ __launch_bounds__(256, 4) void gemm2_k(
    const unsigned short* __restrict__ hbuf,
    const unsigned short* __restrict__ w2T, const unsigned short* __restrict__ sw2T,
    float* __restrict__ ybuf, float* __restrict__ out,
    const int* __restrict__ tlist, const float* __restrict__ wlist,
    const int* __restrict__ counts) {
  int e, m0, n_e, hb;
  if (!tile_lookup(counts, blockIdx.y, e, m0, n_e, hb)) return;
  const int n0 = blockIdx.x * 64;
  const bool sh = (e == NEXP);
  const unsigned short* Bp = sh ? sw2T : w2T + (size_t)e * 1048576;
  const int* listp = tlist + e * NTOK;

  __shared__ unsigned short As[128 * 64], Bs[64 * 64];
  const int tid = threadIdx.x, lane = tid & 63, wv = tid >> 6;
  const int wrw = wv >> 1, wc = wv & 1, l16 = lane & 15, lq = lane >> 4;

  const unsigned short* ga[4];
#pragma unroll
  for (int i = 0; i < 4; ++i) {
    int c = tid + i * 256;
    int r = c >> 3, ks = (c & 7) ^ (r & 7);
    ga[i] = hbuf + (size_t)(hb + m0 + r) * 1024 + ks * 8;  // padded rows zero-filled
  }
  const unsigned short* gb[2];
#pragma unroll
  for (int i = 0; i < 2; ++i) {
    int c = tid + i * 256;
    int r = c >> 3, ks = (c & 7) ^ (r & 7);
    gb[i] = Bp + (size_t)(n0 + r) * 1024 + ks * 8;
  }
  unsigned short* lA[4];
#pragma unroll
  for (int i = 0; i < 4; ++i) lA[i] = As + i * 2048 + wv * 512;
  unsigned short* lB[2] = {Bs + wv * 512, Bs + 2048 + wv * 512};

  f32x4 acc[4][2];
#pragma unroll
  for (int mi = 0; mi < 4; ++mi)
#pragma unroll
    for (int ni = 0; ni < 2; ++ni)
#pragma unroll
      for (int r = 0; r < 4; ++r) acc[mi][ni][r] = 0.f;

  for (int k0 = 0; k0 < 1024; k0 += 64) {
#pragma unroll
    for (int i = 0; i < 4; ++i) { gll16(ga[i], lA[i]); ga[i] += 64; }
#pragma unroll
    for (int i = 0; i < 2; ++i) { gll16(gb[i], lB[i]); gb[i] += 64; }
    __syncthreads();
#pragma unroll
    for (int kh = 0; kh < 2; ++kh) {
      short8 af[4], bf[2];
#pragma unroll
      for (int mi = 0; mi < 4; ++mi) {
        int R = wrw * 64 + mi * 16 + l16;
        int s = (kh * 4 + lq) ^ (R & 7);
        af[mi] = *(const short8*)&As[R * 64 + s * 8];
      }
#pragma unroll
      for (int ni = 0; ni < 2; ++ni) {
        int R = wc * 32 + ni * 16 + l16;
        int s = (kh * 4 + lq) ^ (R & 7);
        bf[ni] = *(const short8*)&Bs[R * 64 + s * 8];
      }
#pragma unroll
      for (int mi = 0; mi < 4; ++mi)
#pragma unroll
        for (int ni = 0; ni < 2; ++ni)
          acc[mi][ni] = __builtin_amdgcn_mfma_f32_16x16x32_bf16(af[mi], bf[ni], acc[mi][ni], 0, 0, 0);
    }
    __syncthreads();
  }

#pragma unroll
  for (int mi = 0; mi < 4; ++mi)
#pragma unroll
    for (int r = 0; r < 4; ++r) {
      int row = m0 + wrw * 64 + mi * 16 + lq * 4 + r;
      int col = n0 + wc * 32 + l16;
      if (sh) {
        float* yp = out + (size_t)row * 1024 + col;
#pragma unroll
        for (int ni = 0; ni < 2; ++ni) yp[ni * 16] = acc[mi][ni][r] * (1.f / 3.f);
      } else if (row < n_e) {
        int ent = listp[row];
        float wt = wlist[e * NTOK + row] * (2.f / 3.f);
        int tok = ent & 0xFFFF, ks = ent >> 16;
        float* yp = ybuf + ((size_t)ks * NTOK + tok) * 1024 + col;
#pragma unroll
        for (int ni = 0; ni < 2; ++ni) yp[ni * 16] = wt * acc[mi][ni][r];
      }
    }
}

// ---- combine: blocks [0,4096): out += y0 + y1; block 4096: loss reduction ----
__global__ __launch_bounds__(256) void combine_k(const float* __restrict__ y,
                                                 float* __restrict__ out,
                                                 const float* __restrict__ probs,
                                                 const float* __restrict__ lsebuf,
                                                 const int* __restrict__ counts,
                                                 float* __restrict__ lossout) {
  if (blockIdx.x < NTOK * 1024 / 4 / 256) {
    size_t i = (size_t)blockIdx.x * 256 + threadIdx.x;
    const f32x4* y0 = (const f32x4*)y + i;
    const f32x4* y1 = y0 + (NTOK * 1024 / 4);
    f32x4 o = ((f32x4*)out)[i];
    ((f32x4*)out)[i] = o + *y0 + *y1;
    return;
  }
  // loss block (runs concurrently with the adds; reads only prep outputs)
  int t = threadIdx.x, lane = t & 63, wv = t >> 6;
  float pacc[NEXP];
#pragma unroll
  for (int e = 0; e < NEXP; ++e) pacc[e] = 0.f;
  float zacc = 0.f;
#pragma unroll
  for (int it = 0; it < 16; ++it) {
    int tok = t + it * 256;
    f32x4 a = ((const f32x4*)(probs + (size_t)tok * NEXP))[0];
    f32x4 c = ((const f32x4*)(probs + (size_t)tok * NEXP))[1];
#pragma unroll
    for (int j = 0; j < 4; ++j) { pacc[j] += a[j]; pacc[4 + j] += c[j]; }
    float lv = lsebuf[tok];
    zacc += lv * lv;
  }
#pragma unroll
  for (int off = 32; off > 0; off >>= 1) {
#pragma unroll
    for (int e = 0; e < NEXP; ++e) pacc[e] += __shfl_xor(pacc[e], off);
    zacc += __shfl_xor(zacc, off);
  }
  __shared__ float red[4][NEXP + 1];
  if (lane == 0) {
#pragma unroll
    for (int e = 0; e < NEXP; ++e) red[wv][e] = pacc[e];
    red[wv][NEXP] = zacc;
  }
  __syncthreads();
  if (t == 0) {
    float dot = 0.f, z = 0.f;
    for (int e = 0; e < NEXP; ++e) {
      float se = red[0][e] + red[1][e] + red[2][e] + red[3][e];
      dot += (float)counts[e] * se;
    }
    z = red[0][NEXP] + red[1][NEXP] + red[2][NEXP] + red[3][NEXP];
    lossout[0] = 6.103515625e-7f * dot;  // E*LB_W/(NUM_LAYERS*N*K)
    lossout[1] = z * (0.001f / 4096.f);
  }
}

extern "C" void kernel_launch(void* const* d_in, const int* in_sizes, int n_in,
                              void* d_out, int out_size, void* d_ws, size_t ws_size,
                              hipStream_t stream) {
  const float* x   = (const float*)d_in[0];
  const float* wrt = (const float*)d_in[1];
  const float* w1  = (const float*)d_in[2];
  const float* w3  = (const float*)d_in[3];
  const float* w2  = (const float*)d_in[4];
  const float* sw1 = (const float*)d_in[5];
  const float* sw3 = (const float*)d_in[6];
  const float* sw2 = (const float*)d_in[7];
  float* out = (float*)d_out;

  char* p = (char*)d_ws;
  auto alloc = [&](size_t b) { char* r = p; p += (b + 255) & ~(size_t)255; return r; };
  unsigned short* xb   = (unsigned short*)alloc((size_t)NTOK * 1024 * 2);
  // contiguous: w1T(8) w3T(8) w2T(8) sw1T sw3T sw2T = 27 x 1M elems
  unsigned short* w1T  = (unsigned short*)alloc((size_t)27 * 1048576 * 2);
  unsigned short* w3T  = w1T + (size_t)8 * 1048576;
  unsigned short* w2T  = w3T + (size_t)8 * 1048576;
  unsigned short* sw1T = w2T + (size_t)8 * 1048576;
  unsigned short* sw3T = sw1T + 1048576;
  unsigned short* sw2T = sw3T + 1048576;
  unsigned short* hbuf = (unsigned short*)alloc((size_t)13312 * 1024 * 2);
  float* ybuf   = (float*)alloc((size_t)2 * NTOK * 1024 * 4);
  int* tlist    = (int*)alloc((size_t)NEXP * NTOK * 4);
  float* wlist  = (float*)alloc((size_t)NEXP * NTOK * 4);
  float* probs  = (float*)alloc((size_t)NTOK * NEXP * 4);
  float* lsebuf = (float*)alloc((size_t)NTOK * 4);
  int* counts   = (int*)alloc(256);

  hipMemsetAsync(counts, 0, NEXP * 4, stream);

  prep_k<<<5632, 256, 0, stream>>>(w1, w3, sw1, sw3, w1T,
                                   x, wrt, xb, counts, tlist, wlist, probs, lsebuf);
  gemm1_k<<<dim3(16, MAXTILES + 144), 256, 0, stream>>>(
      xb, w1T, w3T, sw1T, sw3T, hbuf, tlist, counts, w2, sw2, w1T);
  gemm2_k<<<dim3(16, MAXTILES), 256, 0, stream>>>(hbuf, w2T, sw2T, ybuf, out,
                                                  tlist, wlist, counts);
  combine_k<<<NTOK * 1024 / 4 / 256 + 1, 256, 0, stream>>>(
      ybuf, out, probs, lsebuf, counts, out + (size_t)NTOK * 1024);
}

// Round 5
// 300.489 us; speedup vs baseline: 1.2403x; 1.2403x over previous
//
#include <hip/hip_runtime.h>

#define NTOK 4096
#define NEXP 8
#define MAXTILES 104

typedef __attribute__((ext_vector_type(8))) short short8;
typedef __attribute__((ext_vector_type(4))) float f32x4;
typedef __attribute__((ext_vector_type(4))) unsigned int uint4v;
typedef __attribute__((ext_vector_type(2))) unsigned int uint2v;

__device__ __forceinline__ unsigned short f2bf(float f) {
  union { float f; unsigned u; } v; v.f = f;
  unsigned u = v.u;
  return (unsigned short)((u + 0x7FFFu + ((u >> 16) & 1u)) >> 16);
}

__device__ __forceinline__ void gll16(const void* g, void* l) {
  __builtin_amdgcn_global_load_lds((const __attribute__((address_space(1))) void*)g,
                                   (__attribute__((address_space(3))) void*)l, 16, 0, 0);
}

// shared 64x64 fp32->bf16 transpose tile body (proven: 0 bank conflicts)
__device__ __forceinline__ void transpose_tile(const float* __restrict__ S,
                                               unsigned short* __restrict__ Dp,
                                               int r0, int c0, int t,
                                               unsigned short (*tile)[65]) {
  int r = t >> 2, cb = (t & 3) * 16;
  const float* sp = S + (size_t)(r0 + r) * 1024 + c0 + cb;
  f32x4 v0 = ((const f32x4*)sp)[0], v1 = ((const f32x4*)sp)[1];
  f32x4 v2 = ((const f32x4*)sp)[2], v3 = ((const f32x4*)sp)[3];
#pragma unroll
  for (int j = 0; j < 4; ++j) {
    tile[r][cb + j] = f2bf(v0[j]);
    tile[r][cb + 4 + j] = f2bf(v1[j]);
    tile[r][cb + 8 + j] = f2bf(v2[j]);
    tile[r][cb + 12 + j] = f2bf(v3[j]);
  }
  __syncthreads();
  unsigned short* dp = Dp + (size_t)(c0 + r) * 1024 + r0 + cb;
  uint4v o0, o1;
#pragma unroll
  for (int j = 0; j < 4; ++j) {
    o0[j] = (unsigned)tile[cb + 2 * j][r] | ((unsigned)tile[cb + 2 * j + 1][r] << 16);
    o1[j] = (unsigned)tile[cb + 8 + 2 * j][r] | ((unsigned)tile[cb + 9 + 2 * j][r] << 16);
  }
  ((uint4v*)dp)[0] = o0;
  ((uint4v*)dp)[1] = o1;
}

// ---- prep: blocks [0,4608) = w1/w3/sw1/sw3 transpose (18 slices); [4608,5632) = router ----
__global__ __launch_bounds__(256) void prep_k(
    const float* __restrict__ w1, const float* __restrict__ w3,
    const float* __restrict__ sw1, const float* __restrict__ sw3,
    unsigned short* __restrict__ dst /* w1T base */,
    const float* __restrict__ x, const float* __restrict__ wr, unsigned short* __restrict__ xb,
    int* __restrict__ rec, float* __restrict__ wts, float* __restrict__ probs,
    float* __restrict__ lsebuf) {
  __shared__ unsigned short tile[64][65];
  int b = blockIdx.x;
  if (b < 4608) {
    int z = b >> 8, rem = b & 255;
    const float* S;
    unsigned short* Dp;
    if (z < 8) { S = w1 + (size_t)z * 1048576; Dp = dst + (size_t)z * 1048576; }
    else if (z < 16) { S = w3 + (size_t)(z - 8) * 1048576; Dp = dst + (size_t)z * 1048576; }
    else if (z == 16) { S = sw1; Dp = dst + (size_t)24 * 1048576; }
    else { S = sw3; Dp = dst + (size_t)25 * 1048576; }
    transpose_tile(S, Dp, (rem >> 4) * 64, (rem & 15) * 64, threadIdx.x, tile);
  } else {
    int t = threadIdx.x, lane = t & 63, wv = t >> 6;
    int tok = (b - 4608) * 4 + wv;
    const f32x4* x4 = (const f32x4*)(x + (size_t)tok * 1024);
    f32x4 xv[4];
#pragma unroll
    for (int j = 0; j < 4; ++j) xv[j] = x4[j * 64 + lane];

    unsigned short* xo = xb + (size_t)tok * 1024;
#pragma unroll
    for (int j = 0; j < 4; ++j) {
      uint2v o;
      o[0] = (unsigned)f2bf(xv[j][0]) | ((unsigned)f2bf(xv[j][1]) << 16);
      o[1] = (unsigned)f2bf(xv[j][2]) | ((unsigned)f2bf(xv[j][3]) << 16);
      *(uint2v*)(xo + j * 256 + lane * 4) = o;
    }

    float acc[NEXP];
#pragma unroll
    for (int e = 0; e < NEXP; ++e) acc[e] = 0.f;
#pragma unroll
    for (int j = 0; j < 4; ++j) {
      int base = j * 256 + lane * 4;
#pragma unroll
      for (int c = 0; c < 4; ++c) {
        float xf = xv[j][c];
        const f32x4* wp = (const f32x4*)(wr + (size_t)(base + c) * NEXP);
        f32x4 q0 = wp[0], q1 = wp[1];
#pragma unroll
        for (int e = 0; e < 4; ++e) { acc[e] += xf * q0[e]; acc[4 + e] += xf * q1[e]; }
      }
    }
#pragma unroll
    for (int off = 32; off > 0; off >>= 1) {
#pragma unroll
      for (int e = 0; e < NEXP; ++e) acc[e] += __shfl_xor(acc[e], off);
    }

    float mx = acc[0];
#pragma unroll
    for (int e = 1; e < NEXP; ++e) mx = fmaxf(mx, acc[e]);
    float s = 0.f;
#pragma unroll
    for (int e = 0; e < NEXP; ++e) s += __expf(acc[e] - mx);
    float inv = 1.f / s;

    if (lane < NEXP) probs[(size_t)tok * NEXP + lane] = __expf(acc[lane] - mx) * inv;
    if (lane == 0) {
      int i0 = 0; float v0 = acc[0];
#pragma unroll
      for (int e = 1; e < NEXP; ++e) if (acc[e] > v0) { v0 = acc[e]; i0 = e; }
      int i1 = -1; float v1 = -3.4e38f;
#pragma unroll
      for (int e = 0; e < NEXP; ++e) if (e != i0 && acc[e] > v1) { v1 = acc[e]; i1 = e; }
      rec[tok] = i0 | (i1 << 8);
      wts[2 * tok] = __expf(v0 - mx) * inv;
      wts[2 * tok + 1] = __expf(v1 - mx) * inv;
      lsebuf[tok] = mx + __logf(s);
    }
  }
}

// ---- build: SINGLE block — lists via LDS counters, ebase/tiles/counts/losses ----
// (global hot-address atomics proven poisonous: R3 gemm2-epilogue, R4 router — keep LDS counters)
__global__ __launch_bounds__(1024) void build_k(
    const int* __restrict__ rec, const float* __restrict__ wts, const float* __restrict__ probs,
    const float* __restrict__ lsebuf,
    int* __restrict__ tlist, float* __restrict__ wlist,
    int* __restrict__ counts, int* __restrict__ ebase, int* __restrict__ tiles,
    float* __restrict__ lossout) {
  __shared__ int lcnt[NEXP];
  __shared__ float sprob[NEXP];
  __shared__ float sz;
  int t = threadIdx.x, lane = t & 63;
  if (t < NEXP) { lcnt[t] = 0; sprob[t] = 0.f; }
  if (t == 0) sz = 0.f;
  __syncthreads();

  float pacc[NEXP];
#pragma unroll
  for (int e = 0; e < NEXP; ++e) pacc[e] = 0.f;
  float zacc = 0.f;

#pragma unroll
  for (int it = 0; it < 4; ++it) {
    int tok = t + it * 1024;
    int r = rec[tok];
    int i0 = r & 255, i1 = (r >> 8) & 255;
    int p0 = atomicAdd(&lcnt[i0], 1);
    tlist[i0 * NTOK + p0] = tok;
    wlist[i0 * NTOK + p0] = wts[2 * tok];
    int p1 = atomicAdd(&lcnt[i1], 1);
    tlist[i1 * NTOK + p1] = tok | (1 << 16);
    wlist[i1 * NTOK + p1] = wts[2 * tok + 1];
    f32x4 a = ((const f32x4*)(probs + (size_t)tok * NEXP))[0];
    f32x4 c = ((const f32x4*)(probs + (size_t)tok * NEXP))[1];
#pragma unroll
    for (int j = 0; j < 4; ++j) { pacc[j] += a[j]; pacc[4 + j] += c[j]; }
    float lv = lsebuf[tok];
    zacc += lv * lv;
  }
#pragma unroll
  for (int off = 32; off > 0; off >>= 1) {
#pragma unroll
    for (int e = 0; e < NEXP; ++e) pacc[e] += __shfl_xor(pacc[e], off);
    zacc += __shfl_xor(zacc, off);
  }
  if (lane == 0) {
#pragma unroll
    for (int e = 0; e < NEXP; ++e) atomicAdd(&sprob[e], pacc[e]);
    atomicAdd(&sz, zacc);
  }
  __syncthreads();

  if (t == 0) {
    int a = 0, tt = 0;
    float dot = 0.f;
    for (int e = 0; e < NEXP; ++e) {
      counts[e] = lcnt[e];
      ebase[e] = a;
      int nt = (lcnt[e] + 127) >> 7;
      for (int i = 0; i < nt; ++i) tiles[tt++] = (e << 16) | i;
      a += nt * 128;
      dot += (float)lcnt[e] * sprob[e];
    }
    ebase[NEXP] = a;
    for (int i = 0; i < 32; ++i) tiles[tt++] = (NEXP << 16) | i;
    while (tt < MAXTILES) tiles[tt++] = -1;
    lossout[0] = 6.103515625e-7f * dot;  // E*LB_W/(NUM_LAYERS*N*K)
    lossout[1] = sz * (0.001f / 4096.f);
  }
}

// ---- GEMM1: y<MAXTILES: 128x64 dual-B SwiGLU tiles; y>=MAXTILES: w2/sw2 transpose ----
// launch_bounds (256,3): proven optimum — 4 blocks/CU thrashes L2 (R2: FETCH 117->205MB, 2x dur)
// R5: chunked XCD swizzle on GEMM tiles (grid 16x104=1664=8*208, bijective)
__global__ __launch_bounds__(256, 3) void gemm1_k(
    const unsigned short* __restrict__ xb,
    const unsigned short* __restrict__ w1T, const unsigned short* __restrict__ w3T,
    const unsigned short* __restrict__ sw1T, const unsigned short* __restrict__ sw3T,
    unsigned short* __restrict__ hout,
    const int* __restrict__ tlist, const int* __restrict__ counts,
    const int* __restrict__ ebase, const int* __restrict__ tiles,
    const float* __restrict__ w2, const float* __restrict__ sw2,
    unsigned short* __restrict__ wTbase /* = w1T; w2T at +16M, sw2T at +26M */) {
  __shared__ unsigned short As[128 * 64], Bs1[64 * 64], Bs3[64 * 64];
  const int tid = threadIdx.x;

  if (blockIdx.y >= MAXTILES) {
    // ---- w2/sw2 transpose: 9 slices x 256 tiles ----
    int tb = (blockIdx.y - MAXTILES) * 16 + blockIdx.x;  // 0..2303
    int z = tb >> 8, rem = tb & 255;
    const float* S = (z < 8) ? w2 + (size_t)z * 1048576 : sw2;
    unsigned short* Dp = (z < 8) ? wTbase + (size_t)(16 + z) * 1048576
                                 : wTbase + (size_t)26 * 1048576;
    transpose_tile(S, Dp, (rem >> 4) * 64, (rem & 15) * 64, tid,
                   (unsigned short (*)[65])As);
    return;
  }

  // XCD-aware chunked swizzle: hw bid%8 = XCD; give each XCD 208 contiguous logical tiles
  int bid = blockIdx.y * 16 + blockIdx.x;
  int swz = (bid & 7) * 208 + (bid >> 3);
  int ty = swz >> 4, tx = swz & 15;

  int td = tiles[ty];
  if (td < 0) return;
  const int e = td >> 16;
  const int m0 = (td & 0xFFFF) << 7;
  const int n0 = tx * 64;
  const bool sh = (e == NEXP);
  const int n_e = sh ? NTOK : counts[e];
  const int hb = ebase[e];
  const unsigned short* B1p = sh ? sw1T : w1T + (size_t)e * 1048576;
  const unsigned short* B3p = sh ? sw3T : w3T + (size_t)e * 1048576;
  const int* listp = tlist + e * NTOK;

  const int lane = tid & 63, wv = tid >> 6;
  const int wrw = wv >> 1, wc = wv & 1, l16 = lane & 15, lq = lane >> 4;

  const unsigned short* ga[4];
#pragma unroll
  for (int i = 0; i < 4; ++i) {
    int c = tid + i * 256;
    int r = c >> 3, ks = (c & 7) ^ (r & 7);
    int ar = m0 + r;
    int rowA = sh ? ar : (ar < n_e ? (listp[ar] & 0xFFFF) : 0);
    ga[i] = xb + (size_t)rowA * 1024 + ks * 8;
  }
  const unsigned short* gb[2];
  const unsigned short* gc[2];
#pragma unroll
  for (int i = 0; i < 2; ++i) {
    int c = tid + i * 256;
    int r = c >> 3, ks = (c & 7) ^ (r & 7);
    gb[i] = B1p + (size_t)(n0 + r) * 1024 + ks * 8;
    gc[i] = B3p + (size_t)(n0 + r) * 1024 + ks * 8;
  }
  unsigned short* lA[4];
#pragma unroll
  for (int i = 0; i < 4; ++i) lA[i] = As + i * 2048 + wv * 512;
  unsigned short* lB[2] = {Bs1 + wv * 512, Bs1 + 2048 + wv * 512};
  unsigned short* lC[2] = {Bs3 + wv * 512, Bs3 + 2048 + wv * 512};

  f32x4 accg[4][2], accu[4][2];
#pragma unroll
  for (int mi = 0; mi < 4; ++mi)
#pragma unroll
    for (int ni = 0; ni < 2; ++ni)
#pragma unroll
      for (int r = 0; r < 4; ++r) { accg[mi][ni][r] = 0.f; accu[mi][ni][r] = 0.f; }

  for (int k0 = 0; k0 < 1024; k0 += 64) {
#pragma unroll
    for (int i = 0; i < 4; ++i) { gll16(ga[i], lA[i]); ga[i] += 64; }
#pragma unroll
    for (int i = 0; i < 2; ++i) { gll16(gb[i], lB[i]); gb[i] += 64; gll16(gc[i], lC[i]); gc[i] += 64; }
    __syncthreads();
#pragma unroll
    for (int kh = 0; kh < 2; ++kh) {
      short8 af[4], b1f[2], b3f[2];
#pragma unroll
      for (int mi = 0; mi < 4; ++mi) {
        int R = wrw * 64 + mi * 16 + l16;
        int s = (kh * 4 + lq) ^ (R & 7);
        af[mi] = *(const short8*)&As[R * 64 + s * 8];
      }
#pragma unroll
      for (int ni = 0; ni < 2; ++ni) {
        int R = wc * 32 + ni * 16 + l16;
        int s = (kh * 4 + lq) ^ (R & 7);
        b1f[ni] = *(const short8*)&Bs1[R * 64 + s * 8];
        b3f[ni] = *(const short8*)&Bs3[R * 64 + s * 8];
      }
#pragma unroll
      for (int mi = 0; mi < 4; ++mi)
#pragma unroll
        for (int ni = 0; ni < 2; ++ni) {
          accg[mi][ni] = __builtin_amdgcn_mfma_f32_16x16x32_bf16(af[mi], b1f[ni], accg[mi][ni], 0, 0, 0);
          accu[mi][ni] = __builtin_amdgcn_mfma_f32_16x16x32_bf16(af[mi], b3f[ni], accu[mi][ni], 0, 0, 0);
        }
    }
    __syncthreads();
  }

#pragma unroll
  for (int mi = 0; mi < 4; ++mi)
#pragma unroll
    for (int ni = 0; ni < 2; ++ni) {
      int col = n0 + wc * 32 + ni * 16 + l16;
#pragma unroll
      for (int r = 0; r < 4; ++r) {
        int row = m0 + wrw * 64 + mi * 16 + lq * 4 + r;
        float g = accg[mi][ni][r], u = accu[mi][ni][r];
        float h = g / (1.f + __expf(-g)) * u;
        hout[(size_t)(hb + row) * 1024 + col] = (row < n_e) ? f2bf(h) : (unsigned short)0;
      }
    }
}

// ---- GEMM2: 128x64 tile, BK=64; expert tiles -> ybuf[k] slices, shared tiles -> out ----
__global__ __launch_bounds__(256, 4) void gemm2_k(
    const unsigned short* __restrict__ hbuf,
    const unsigned short* __restrict__ w2T, const unsigned short* __restrict__ sw2T,
    float* __restrict__ ybuf, float* __restrict__ out,
    const int* __restrict__ tlist, const float* __restrict__ wlist,
    const int* __restrict__ counts, const int* __restrict__ ebase, const int* __restrict__ tiles) {
  // XCD-aware chunked swizzle (grid 16x104 = 1664 = 8*208, bijective)
  int bid = blockIdx.y * 16 + blockIdx.x;
  int swz = (bid & 7) * 208 + (bid >> 3);
  int ty = swz >> 4, tx = swz & 15;

  int td = tiles[ty];
  if (td < 0) return;
  const int e = td >> 16;
  const int m0 = (td & 0xFFFF) << 7;
  const int n0 = tx * 64;
  const bool sh = (e == NEXP);
  const int n_e = sh ? NTOK : counts[e];
  const int hb = ebase[e];
  const unsigned short* Bp = sh ? sw2T : w2T + (size_t)e * 1048576;
  const int* listp = tlist + e * NTOK;

  __shared__ unsigned short As[128 * 64], Bs[64 * 64];
  const int tid = threadIdx.x, lane = tid & 63, wv = tid >> 6;
  const int wrw = wv >> 1, wc = wv & 1, l16 = lane & 15, lq = lane >> 4;

  const unsigned short* ga[4];
#pragma unroll
  for (int i = 0; i < 4; ++i) {
    int c = tid + i * 256;
    int r = c >> 3, ks = (c & 7) ^ (r & 7);
    ga[i] = hbuf + (size_t)(hb + m0 + r) * 1024 + ks * 8;  // padded rows zero-filled
  }
  const unsigned short* gb[2];
#pragma unroll
  for (int i = 0; i < 2; ++i) {
    int c = tid + i * 256;
    int r = c >> 3, ks = (c & 7) ^ (r & 7);
    gb[i] = Bp + (size_t)(n0 + r) * 1024 + ks * 8;
  }
  unsigned short* lA[4];
#pragma unroll
  for (int i = 0; i < 4; ++i) lA[i] = As + i * 2048 + wv * 512;
  unsigned short* lB[2] = {Bs + wv * 512, Bs + 2048 + wv * 512};

  f32x4 acc[4][2];
#pragma unroll
  for (int mi = 0; mi < 4; ++mi)
#pragma unroll
    for (int ni = 0; ni < 2; ++ni)
#pragma unroll
      for (int r = 0; r < 4; ++r) acc[mi][ni][r] = 0.f;

  for (int k0 = 0; k0 < 1024; k0 += 64) {
#pragma unroll
    for (int i = 0; i < 4; ++i) { gll16(ga[i], lA[i]); ga[i] += 64; }
#pragma unroll
    for (int i = 0; i < 2; ++i) { gll16(gb[i], lB[i]); gb[i] += 64; }
    __syncthreads();
#pragma unroll
    for (int kh = 0; kh < 2; ++kh) {
      short8 af[4], bf[2];
#pragma unroll
      for (int mi = 0; mi < 4; ++mi) {
        int R = wrw * 64 + mi * 16 + l16;
        int s = (kh * 4 + lq) ^ (R & 7);
        af[mi] = *(const short8*)&As[R * 64 + s * 8];
      }
#pragma unroll
      for (int ni = 0; ni < 2; ++ni) {
        int R = wc * 32 + ni * 16 + l16;
        int s = (kh * 4 + lq) ^ (R & 7);
        bf[ni] = *(const short8*)&Bs[R * 64 + s * 8];
      }
#pragma unroll
      for (int mi = 0; mi < 4; ++mi)
#pragma unroll
        for (int ni = 0; ni < 2; ++ni)
          acc[mi][ni] = __builtin_amdgcn_mfma_f32_16x16x32_bf16(af[mi], bf[ni], acc[mi][ni], 0, 0, 0);
    }
    __syncthreads();
  }

#pragma unroll
  for (int mi = 0; mi < 4; ++mi)
#pragma unroll
    for (int r = 0; r < 4; ++r) {
      int row = m0 + wrw * 64 + mi * 16 + lq * 4 + r;
      int col = n0 + wc * 32 + l16;
      if (sh) {
        float* yp = out + (size_t)row * 1024 + col;
#pragma unroll
        for (int ni = 0; ni < 2; ++ni) yp[ni * 16] = acc[mi][ni][r] * (1.f / 3.f);
      } else if (row < n_e) {
        int ent = listp[row];
        float wt = wlist[e * NTOK + row] * (2.f / 3.f);
        int tok = ent & 0xFFFF, ks = ent >> 16;
        float* yp = ybuf + ((size_t)ks * NTOK + tok) * 1024 + col;
#pragma unroll
        for (int ni = 0; ni < 2; ++ni) yp[ni * 16] = wt * acc[mi][ni][r];
      }
    }
}

// ---- combine: out += y0 + y1 (shared part already in out; scales folded) ----
__global__ __launch_bounds__(256) void combine_k(const float* __restrict__ y,
                                                 float* __restrict__ out) {
  size_t i = (size_t)blockIdx.x * 256 + threadIdx.x;
  const f32x4* y0 = (const f32x4*)y + i;
  const f32x4* y1 = y0 + (NTOK * 1024 / 4);
  f32x4 o = ((f32x4*)out)[i];
  ((f32x4*)out)[i] = o + *y0 + *y1;
}

extern "C" void kernel_launch(void* const* d_in, const int* in_sizes, int n_in,
                              void* d_out, int out_size, void* d_ws, size_t ws_size,
                              hipStream_t stream) {
  const float* x   = (const float*)d_in[0];
  const float* wrt = (const float*)d_in[1];
  const float* w1  = (const float*)d_in[2];
  const float* w3  = (const float*)d_in[3];
  const float* w2  = (const float*)d_in[4];
  const float* sw1 = (const float*)d_in[5];
  const float* sw3 = (const float*)d_in[6];
  const float* sw2 = (const float*)d_in[7];
  float* out = (float*)d_out;

  char* p = (char*)d_ws;
  auto alloc = [&](size_t b) { char* r = p; p += (b + 255) & ~(size_t)255; return r; };
  unsigned short* xb   = (unsigned short*)alloc((size_t)NTOK * 1024 * 2);
  // contiguous: w1T(8) w3T(8) w2T(8) sw1T sw3T sw2T = 27 x 1M elems
  unsigned short* w1T  = (unsigned short*)alloc((size_t)27 * 1048576 * 2);
  unsigned short* w3T  = w1T + (size_t)8 * 1048576;
  unsigned short* w2T  = w3T + (size_t)8 * 1048576;
  unsigned short* sw1T = w2T + (size_t)8 * 1048576;
  unsigned short* sw3T = sw1T + 1048576;
  unsigned short* sw2T = sw3T + 1048576;
  unsigned short* hbuf = (unsigned short*)alloc((size_t)13312 * 1024 * 2);
  float* ybuf   = (float*)alloc((size_t)2 * NTOK * 1024 * 4);
  int* tlist    = (int*)alloc((size_t)NEXP * NTOK * 4);
  float* wlist  = (float*)alloc((size_t)NEXP * NTOK * 4);
  int* rec      = (int*)alloc((size_t)NTOK * 4);
  float* wts    = (float*)alloc((size_t)NTOK * 2 * 4);
  float* probs  = (float*)alloc((size_t)NTOK * NEXP * 4);
  float* lsebuf = (float*)alloc((size_t)NTOK * 4);
  int* tiles    = (int*)alloc(MAXTILES * 4);
  int* ebase    = (int*)alloc(256);
  int* counts   = (int*)alloc(256);

  prep_k<<<5632, 256, 0, stream>>>(w1, w3, sw1, sw3, w1T,
                                   x, wrt, xb, rec, wts, probs, lsebuf);
  build_k<<<1, 1024, 0, stream>>>(rec, wts, probs, lsebuf, tlist, wlist,
                                  counts, ebase, tiles, out + (size_t)NTOK * 1024);
  gemm1_k<<<dim3(16, MAXTILES + 144), 256, 0, stream>>>(
      xb, w1T, w3T, sw1T, sw3T, hbuf, tlist, counts, ebase, tiles, w2, sw2, w1T);
  gemm2_k<<<dim3(16, MAXTILES), 256, 0, stream>>>(hbuf, w2T, sw2T, ybuf, out,
                                                  tlist, wlist, counts, ebase, tiles);
  combine_k<<<NTOK * 1024 / 4 / 256, 256, 0, stream>>>(ybuf, out);
}

// Round 6
// 299.388 us; speedup vs baseline: 1.2449x; 1.0037x over previous
//
#include <hip/hip_runtime.h>

#define NTOK 4096
#define NEXP 8
#define MAXTILES 104

typedef __attribute__((ext_vector_type(8))) short short8;
typedef __attribute__((ext_vector_type(4))) float f32x4;
typedef __attribute__((ext_vector_type(4))) unsigned int uint4v;
typedef __attribute__((ext_vector_type(2))) unsigned int uint2v;

__device__ __forceinline__ unsigned short f2bf(float f) {
  union { float f; unsigned u; } v; v.f = f;
  unsigned u = v.u;
  return (unsigned short)((u + 0x7FFFu + ((u >> 16) & 1u)) >> 16);
}

__device__ __forceinline__ void gll16(const void* g, void* l) {
  __builtin_amdgcn_global_load_lds((const __attribute__((address_space(1))) void*)g,
                                   (__attribute__((address_space(3))) void*)l, 16, 0, 0);
}

// shared 64x64 fp32->bf16 transpose tile body (proven: 0 bank conflicts)
__device__ __forceinline__ void transpose_tile(const float* __restrict__ S,
                                               unsigned short* __restrict__ Dp,
                                               int r0, int c0, int t,
                                               unsigned short (*tile)[65]) {
  int r = t >> 2, cb = (t & 3) * 16;
  const float* sp = S + (size_t)(r0 + r) * 1024 + c0 + cb;
  f32x4 v0 = ((const f32x4*)sp)[0], v1 = ((const f32x4*)sp)[1];
  f32x4 v2 = ((const f32x4*)sp)[2], v3 = ((const f32x4*)sp)[3];
#pragma unroll
  for (int j = 0; j < 4; ++j) {
    tile[r][cb + j] = f2bf(v0[j]);
    tile[r][cb + 4 + j] = f2bf(v1[j]);
    tile[r][cb + 8 + j] = f2bf(v2[j]);
    tile[r][cb + 12 + j] = f2bf(v3[j]);
  }
  __syncthreads();
  unsigned short* dp = Dp + (size_t)(c0 + r) * 1024 + r0 + cb;
  uint4v o0, o1;
#pragma unroll
  for (int j = 0; j < 4; ++j) {
    o0[j] = (unsigned)tile[cb + 2 * j][r] | ((unsigned)tile[cb + 2 * j + 1][r] << 16);
    o1[j] = (unsigned)tile[cb + 8 + 2 * j][r] | ((unsigned)tile[cb + 9 + 2 * j][r] << 16);
  }
  ((uint4v*)dp)[0] = o0;
  ((uint4v*)dp)[1] = o1;
}

// ---- prep: blocks [0,4608) = w1/w3/sw1/sw3 transpose (18 slices); [4608,5632) = router ----
__global__ __launch_bounds__(256) void prep_k(
    const float* __restrict__ w1, const float* __restrict__ w3,
    const float* __restrict__ sw1, const float* __restrict__ sw3,
    unsigned short* __restrict__ dst /* w1T base */,
    const float* __restrict__ x, const float* __restrict__ wr, unsigned short* __restrict__ xb,
    int* __restrict__ rec, float* __restrict__ wts, float* __restrict__ probs,
    float* __restrict__ lsebuf) {
  __shared__ unsigned short tile[64][65];
  int b = blockIdx.x;
  if (b < 4608) {
    int z = b >> 8, rem = b & 255;
    const float* S;
    unsigned short* Dp;
    if (z < 8) { S = w1 + (size_t)z * 1048576; Dp = dst + (size_t)z * 1048576; }
    else if (z < 16) { S = w3 + (size_t)(z - 8) * 1048576; Dp = dst + (size_t)z * 1048576; }
    else if (z == 16) { S = sw1; Dp = dst + (size_t)24 * 1048576; }
    else { S = sw3; Dp = dst + (size_t)25 * 1048576; }
    transpose_tile(S, Dp, (rem >> 4) * 64, (rem & 15) * 64, threadIdx.x, tile);
  } else {
    int t = threadIdx.x, lane = t & 63, wv = t >> 6;
    int tok = (b - 4608) * 4 + wv;
    const f32x4* x4 = (const f32x4*)(x + (size_t)tok * 1024);
    f32x4 xv[4];
#pragma unroll
    for (int j = 0; j < 4; ++j) xv[j] = x4[j * 64 + lane];

    unsigned short* xo = xb + (size_t)tok * 1024;
#pragma unroll
    for (int j = 0; j < 4; ++j) {
      uint2v o;
      o[0] = (unsigned)f2bf(xv[j][0]) | ((unsigned)f2bf(xv[j][1]) << 16);
      o[1] = (unsigned)f2bf(xv[j][2]) | ((unsigned)f2bf(xv[j][3]) << 16);
      *(uint2v*)(xo + j * 256 + lane * 4) = o;
    }

    float acc[NEXP];
#pragma unroll
    for (int e = 0; e < NEXP; ++e) acc[e] = 0.f;
#pragma unroll
    for (int j = 0; j < 4; ++j) {
      int base = j * 256 + lane * 4;
#pragma unroll
      for (int c = 0; c < 4; ++c) {
        float xf = xv[j][c];
        const f32x4* wp = (const f32x4*)(wr + (size_t)(base + c) * NEXP);
        f32x4 q0 = wp[0], q1 = wp[1];
#pragma unroll
        for (int e = 0; e < 4; ++e) { acc[e] += xf * q0[e]; acc[4 + e] += xf * q1[e]; }
      }
    }
#pragma unroll
    for (int off = 32; off > 0; off >>= 1) {
#pragma unroll
      for (int e = 0; e < NEXP; ++e) acc[e] += __shfl_xor(acc[e], off);
    }

    float mx = acc[0];
#pragma unroll
    for (int e = 1; e < NEXP; ++e) mx = fmaxf(mx, acc[e]);
    float s = 0.f;
#pragma unroll
    for (int e = 0; e < NEXP; ++e) s += __expf(acc[e] - mx);
    float inv = 1.f / s;

    if (lane < NEXP) probs[(size_t)tok * NEXP + lane] = __expf(acc[lane] - mx) * inv;
    if (lane == 0) {
      int i0 = 0; float v0 = acc[0];
#pragma unroll
      for (int e = 1; e < NEXP; ++e) if (acc[e] > v0) { v0 = acc[e]; i0 = e; }
      int i1 = -1; float v1 = -3.4e38f;
#pragma unroll
      for (int e = 0; e < NEXP; ++e) if (e != i0 && acc[e] > v1) { v1 = acc[e]; i1 = e; }
      rec[tok] = i0 | (i1 << 8);
      wts[2 * tok] = __expf(v0 - mx) * inv;
      wts[2 * tok + 1] = __expf(v1 - mx) * inv;
      lsebuf[tok] = mx + __logf(s);
    }
  }
}

// ---- build: SINGLE block — lists via LDS counters, ebase/tiles/counts/losses ----
// (global hot-address atomics proven poisonous: R3 gemm2-epilogue, R4 router — keep LDS counters)
__global__ __launch_bounds__(1024) void build_k(
    const int* __restrict__ rec, const float* __restrict__ wts, const float* __restrict__ probs,
    const float* __restrict__ lsebuf,
    int* __restrict__ tlist, float* __restrict__ wlist,
    int* __restrict__ counts, int* __restrict__ ebase, int* __restrict__ tiles,
    float* __restrict__ lossout) {
  __shared__ int lcnt[NEXP];
  __shared__ float sprob[NEXP];
  __shared__ float sz;
  int t = threadIdx.x, lane = t & 63;
  if (t < NEXP) { lcnt[t] = 0; sprob[t] = 0.f; }
  if (t == 0) sz = 0.f;
  __syncthreads();

  float pacc[NEXP];
#pragma unroll
  for (int e = 0; e < NEXP; ++e) pacc[e] = 0.f;
  float zacc = 0.f;

#pragma unroll
  for (int it = 0; it < 4; ++it) {
    int tok = t + it * 1024;
    int r = rec[tok];
    int i0 = r & 255, i1 = (r >> 8) & 255;
    int p0 = atomicAdd(&lcnt[i0], 1);
    tlist[i0 * NTOK + p0] = tok;
    wlist[i0 * NTOK + p0] = wts[2 * tok];
    int p1 = atomicAdd(&lcnt[i1], 1);
    tlist[i1 * NTOK + p1] = tok | (1 << 16);
    wlist[i1 * NTOK + p1] = wts[2 * tok + 1];
    f32x4 a = ((const f32x4*)(probs + (size_t)tok * NEXP))[0];
    f32x4 c = ((const f32x4*)(probs + (size_t)tok * NEXP))[1];
#pragma unroll
    for (int j = 0; j < 4; ++j) { pacc[j] += a[j]; pacc[4 + j] += c[j]; }
    float lv = lsebuf[tok];
    zacc += lv * lv;
  }
#pragma unroll
  for (int off = 32; off > 0; off >>= 1) {
#pragma unroll
    for (int e = 0; e < NEXP; ++e) pacc[e] += __shfl_xor(pacc[e], off);
    zacc += __shfl_xor(zacc, off);
  }
  if (lane == 0) {
#pragma unroll
    for (int e = 0; e < NEXP; ++e) atomicAdd(&sprob[e], pacc[e]);
    atomicAdd(&sz, zacc);
  }
  __syncthreads();

  if (t == 0) {
    int a = 0, tt = 0;
    float dot = 0.f;
    for (int e = 0; e < NEXP; ++e) {
      counts[e] = lcnt[e];
      ebase[e] = a;
      int nt = (lcnt[e] + 127) >> 7;
      for (int i = 0; i < nt; ++i) tiles[tt++] = (e << 16) | i;
      a += nt * 128;
      dot += (float)lcnt[e] * sprob[e];
    }
    ebase[NEXP] = a;
    for (int i = 0; i < 32; ++i) tiles[tt++] = (NEXP << 16) | i;
    while (tt < MAXTILES) tiles[tt++] = -1;
    lossout[0] = 6.103515625e-7f * dot;  // E*LB_W/(NUM_LAYERS*N*K)
    lossout[1] = sz * (0.001f / 4096.f);
  }
}

// ---- GEMM1: y<MAXTILES: 128x64 dual-B SwiGLU tiles; y>=MAXTILES: w2/sw2 transpose ----
// launch_bounds (256,3): proven optimum — 4 blocks/CU thrashes L2 (R2: FETCH 117->205MB, 2x dur)
// chunked XCD swizzle (R5): FETCH -24%, dur neutral (structure-bound, not BW-bound)
__global__ __launch_bounds__(256, 3) void gemm1_k(
    const unsigned short* __restrict__ xb,
    const unsigned short* __restrict__ w1T, const unsigned short* __restrict__ w3T,
    const unsigned short* __restrict__ sw1T, const unsigned short* __restrict__ sw3T,
    unsigned short* __restrict__ hout,
    const int* __restrict__ tlist, const int* __restrict__ counts,
    const int* __restrict__ ebase, const int* __restrict__ tiles,
    const float* __restrict__ w2, const float* __restrict__ sw2,
    unsigned short* __restrict__ wTbase /* = w1T; w2T at +16M, sw2T at +26M */) {
  __shared__ unsigned short As[128 * 64], Bs1[64 * 64], Bs3[64 * 64];
  const int tid = threadIdx.x;

  if (blockIdx.y >= MAXTILES) {
    // ---- w2/sw2 transpose: 9 slices x 256 tiles ----
    int tb = (blockIdx.y - MAXTILES) * 16 + blockIdx.x;  // 0..2303
    int z = tb >> 8, rem = tb & 255;
    const float* S = (z < 8) ? w2 + (size_t)z * 1048576 : sw2;
    unsigned short* Dp = (z < 8) ? wTbase + (size_t)(16 + z) * 1048576
                                 : wTbase + (size_t)26 * 1048576;
    transpose_tile(S, Dp, (rem >> 4) * 64, (rem & 15) * 64, tid,
                   (unsigned short (*)[65])As);
    return;
  }

  // XCD-aware chunked swizzle: hw bid%8 = XCD; give each XCD 208 contiguous logical tiles
  int bid = blockIdx.y * 16 + blockIdx.x;
  int swz = (bid & 7) * 208 + (bid >> 3);
  int ty = swz >> 4, tx = swz & 15;

  int td = tiles[ty];
  if (td < 0) return;
  const int e = td >> 16;
  const int m0 = (td & 0xFFFF) << 7;
  const int n0 = tx * 64;
  const bool sh = (e == NEXP);
  const int n_e = sh ? NTOK : counts[e];
  const int hb = ebase[e];
  const unsigned short* B1p = sh ? sw1T : w1T + (size_t)e * 1048576;
  const unsigned short* B3p = sh ? sw3T : w3T + (size_t)e * 1048576;
  const int* listp = tlist + e * NTOK;

  const int lane = tid & 63, wv = tid >> 6;
  const int wrw = wv >> 1, wc = wv & 1, l16 = lane & 15, lq = lane >> 4;

  const unsigned short* ga[4];
#pragma unroll
  for (int i = 0; i < 4; ++i) {
    int c = tid + i * 256;
    int r = c >> 3, ks = (c & 7) ^ (r & 7);
    int ar = m0 + r;
    int rowA = sh ? ar : (ar < n_e ? (listp[ar] & 0xFFFF) : 0);
    ga[i] = xb + (size_t)rowA * 1024 + ks * 8;
  }
  const unsigned short* gb[2];
  const unsigned short* gc[2];
#pragma unroll
  for (int i = 0; i < 2; ++i) {
    int c = tid + i * 256;
    int r = c >> 3, ks = (c & 7) ^ (r & 7);
    gb[i] = B1p + (size_t)(n0 + r) * 1024 + ks * 8;
    gc[i] = B3p + (size_t)(n0 + r) * 1024 + ks * 8;
  }
  unsigned short* lA[4];
#pragma unroll
  for (int i = 0; i < 4; ++i) lA[i] = As + i * 2048 + wv * 512;
  unsigned short* lB[2] = {Bs1 + wv * 512, Bs1 + 2048 + wv * 512};
  unsigned short* lC[2] = {Bs3 + wv * 512, Bs3 + 2048 + wv * 512};

  f32x4 accg[4][2], accu[4][2];
#pragma unroll
  for (int mi = 0; mi < 4; ++mi)
#pragma unroll
    for (int ni = 0; ni < 2; ++ni)
#pragma unroll
      for (int r = 0; r < 4; ++r) { accg[mi][ni][r] = 0.f; accu[mi][ni][r] = 0.f; }

  for (int k0 = 0; k0 < 1024; k0 += 64) {
#pragma unroll
    for (int i = 0; i < 4; ++i) { gll16(ga[i], lA[i]); ga[i] += 64; }
#pragma unroll
    for (int i = 0; i < 2; ++i) { gll16(gb[i], lB[i]); gb[i] += 64; gll16(gc[i], lC[i]); gc[i] += 64; }
    __syncthreads();
#pragma unroll
    for (int kh = 0; kh < 2; ++kh) {
      short8 af[4], b1f[2], b3f[2];
#pragma unroll
      for (int mi = 0; mi < 4; ++mi) {
        int R = wrw * 64 + mi * 16 + l16;
        int s = (kh * 4 + lq) ^ (R & 7);
        af[mi] = *(const short8*)&As[R * 64 + s * 8];
      }
#pragma unroll
      for (int ni = 0; ni < 2; ++ni) {
        int R = wc * 32 + ni * 16 + l16;
        int s = (kh * 4 + lq) ^ (R & 7);
        b1f[ni] = *(const short8*)&Bs1[R * 64 + s * 8];
        b3f[ni] = *(const short8*)&Bs3[R * 64 + s * 8];
      }
#pragma unroll
      for (int mi = 0; mi < 4; ++mi)
#pragma unroll
        for (int ni = 0; ni < 2; ++ni) {
          accg[mi][ni] = __builtin_amdgcn_mfma_f32_16x16x32_bf16(af[mi], b1f[ni], accg[mi][ni], 0, 0, 0);
          accu[mi][ni] = __builtin_amdgcn_mfma_f32_16x16x32_bf16(af[mi], b3f[ni], accu[mi][ni], 0, 0, 0);
        }
    }
    __syncthreads();
  }

#pragma unroll
  for (int mi = 0; mi < 4; ++mi)
#pragma unroll
    for (int ni = 0; ni < 2; ++ni) {
      int col = n0 + wc * 32 + ni * 16 + l16;
#pragma unroll
      for (int r = 0; r < 4; ++r) {
        int row = m0 + wrw * 64 + mi * 16 + lq * 4 + r;
        float g = accg[mi][ni][r], u = accu[mi][ni][r];
        float h = g / (1.f + __expf(-g)) * u;
        hout[(size_t)(hb + row) * 1024 + col] = (row < n_e) ? f2bf(h) : (unsigned short)0;
      }
    }
}

// ---- GEMM2: 128x128 tile (R6), BK=64; expert tiles -> ybuf[k] slices, shared -> out ----
// doubled N-extent: same A staging, 2x MFMA per staged byte (match gemm1's density)
__global__ __launch_bounds__(256, 3) void gemm2_k(
    const unsigned short* __restrict__ hbuf,
    const unsigned short* __restrict__ w2T, const unsigned short* __restrict__ sw2T,
    float* __restrict__ ybuf, float* __restrict__ out,
    const int* __restrict__ tlist, const float* __restrict__ wlist,
    const int* __restrict__ counts, const int* __restrict__ ebase, const int* __restrict__ tiles) {
  // XCD-aware chunked swizzle (grid 8x104 = 832 = 8*104, bijective)
  int bid = blockIdx.y * 8 + blockIdx.x;
  int swz = (bid & 7) * 104 + (bid >> 3);
  int ty = swz >> 3, tx = swz & 7;

  int td = tiles[ty];
  if (td < 0) return;
  const int e = td >> 16;
  const int m0 = (td & 0xFFFF) << 7;
  const int n0 = tx * 128;
  const bool sh = (e == NEXP);
  const int n_e = sh ? NTOK : counts[e];
  const int hb = ebase[e];
  const unsigned short* Bp = sh ? sw2T : w2T + (size_t)e * 1048576;
  const int* listp = tlist + e * NTOK;

  __shared__ unsigned short As[128 * 64], Bs[128 * 64];
  const int tid = threadIdx.x, lane = tid & 63, wv = tid >> 6;
  const int wrw = wv >> 1, wc = wv & 1, l16 = lane & 15, lq = lane >> 4;

  const unsigned short* ga[4];
#pragma unroll
  for (int i = 0; i < 4; ++i) {
    int c = tid + i * 256;
    int r = c >> 3, ks = (c & 7) ^ (r & 7);
    ga[i] = hbuf + (size_t)(hb + m0 + r) * 1024 + ks * 8;  // padded rows zero-filled
  }
  const unsigned short* gb[4];
#pragma unroll
  for (int i = 0; i < 4; ++i) {
    int c = tid + i * 256;
    int r = c >> 3, ks = (c & 7) ^ (r & 7);
    gb[i] = Bp + (size_t)(n0 + r) * 1024 + ks * 8;
  }
  unsigned short* lA[4];
  unsigned short* lB[4];
#pragma unroll
  for (int i = 0; i < 4; ++i) {
    lA[i] = As + i * 2048 + wv * 512;
    lB[i] = Bs + i * 2048 + wv * 512;
  }

  f32x4 acc[4][4];
#pragma unroll
  for (int mi = 0; mi < 4; ++mi)
#pragma unroll
    for (int ni = 0; ni < 4; ++ni)
#pragma unroll
      for (int r = 0; r < 4; ++r) acc[mi][ni][r] = 0.f;

  for (int k0 = 0; k0 < 1024; k0 += 64) {
#pragma unroll
    for (int i = 0; i < 4; ++i) { gll16(ga[i], lA[i]); ga[i] += 64; gll16(gb[i], lB[i]); gb[i] += 64; }
    __syncthreads();
#pragma unroll
    for (int kh = 0; kh < 2; ++kh) {
      short8 af[4], bf[4];
#pragma unroll
      for (int mi = 0; mi < 4; ++mi) {
        int R = wrw * 64 + mi * 16 + l16;
        int s = (kh * 4 + lq) ^ (R & 7);
        af[mi] = *(const short8*)&As[R * 64 + s * 8];
      }
#pragma unroll
      for (int ni = 0; ni < 4; ++ni) {
        int R = wc * 64 + ni * 16 + l16;
        int s = (kh * 4 + lq) ^ (R & 7);
        bf[ni] = *(const short8*)&Bs[R * 64 + s * 8];
      }
#pragma unroll
      for (int mi = 0; mi < 4; ++mi)
#pragma unroll
        for (int ni = 0; ni < 4; ++ni)
          acc[mi][ni] = __builtin_amdgcn_mfma_f32_16x16x32_bf16(af[mi], bf[ni], acc[mi][ni], 0, 0, 0);
    }
    __syncthreads();
  }

#pragma unroll
  for (int mi = 0; mi < 4; ++mi)
#pragma unroll
    for (int r = 0; r < 4; ++r) {
      int row = m0 + wrw * 64 + mi * 16 + lq * 4 + r;
      if (sh) {
        float* yp = out + (size_t)row * 1024 + n0 + wc * 64 + l16;
#pragma unroll
        for (int ni = 0; ni < 4; ++ni) yp[ni * 16] = acc[mi][ni][r] * (1.f / 3.f);
      } else if (row < n_e) {
        int ent = listp[row];
        float wt = wlist[e * NTOK + row] * (2.f / 3.f);
        int tok = ent & 0xFFFF, ks = ent >> 16;
        float* yp = ybuf + ((size_t)ks * NTOK + tok) * 1024 + n0 + wc * 64 + l16;
#pragma unroll
        for (int ni = 0; ni < 4; ++ni) yp[ni * 16] = wt * acc[mi][ni][r];
      }
    }
}

// ---- combine: out += y0 + y1 (shared part already in out; scales folded) ----
__global__ __launch_bounds__(256) void combine_k(const float* __restrict__ y,
                                                 float* __restrict__ out) {
  size_t i = (size_t)blockIdx.x * 256 + threadIdx.x;
  const f32x4* y0 = (const f32x4*)y + i;
  const f32x4* y1 = y0 + (NTOK * 1024 / 4);
  f32x4 o = ((f32x4*)out)[i];
  ((f32x4*)out)[i] = o + *y0 + *y1;
}

extern "C" void kernel_launch(void* const* d_in, const int* in_sizes, int n_in,
                              void* d_out, int out_size, void* d_ws, size_t ws_size,
                              hipStream_t stream) {
  const float* x   = (const float*)d_in[0];
  const float* wrt = (const float*)d_in[1];
  const float* w1  = (const float*)d_in[2];
  const float* w3  = (const float*)d_in[3];
  const float* w2  = (const float*)d_in[4];
  const float* sw1 = (const float*)d_in[5];
  const float* sw3 = (const float*)d_in[6];
  const float* sw2 = (const float*)d_in[7];
  float* out = (float*)d_out;

  char* p = (char*)d_ws;
  auto alloc = [&](size_t b) { char* r = p; p += (b + 255) & ~(size_t)255; return r; };
  unsigned short* xb   = (unsigned short*)alloc((size_t)NTOK * 1024 * 2);
  // contiguous: w1T(8) w3T(8) w2T(8) sw1T sw3T sw2T = 27 x 1M elems
  unsigned short* w1T  = (unsigned short*)alloc((size_t)27 * 1048576 * 2);
  unsigned short* w3T  = w1T + (size_t)8 * 1048576;
  unsigned short* w2T  = w3T + (size_t)8 * 1048576;
  unsigned short* sw1T = w2T + (size_t)8 * 1048576;
  unsigned short* sw3T = sw1T + 1048576;
  unsigned short* sw2T = sw3T + 1048576;
  unsigned short* hbuf = (unsigned short*)alloc((size_t)13312 * 1024 * 2);
  float* ybuf   = (float*)alloc((size_t)2 * NTOK * 1024 * 4);
  int* tlist    = (int*)alloc((size_t)NEXP * NTOK * 4);
  float* wlist  = (float*)alloc((size_t)NEXP * NTOK * 4);
  int* rec      = (int*)alloc((size_t)NTOK * 4);
  float* wts    = (float*)alloc((size_t)NTOK * 2 * 4);
  float* probs  = (float*)alloc((size_t)NTOK * NEXP * 4);
  float* lsebuf = (float*)alloc((size_t)NTOK * 4);
  int* tiles    = (int*)alloc(MAXTILES * 4);
  int* ebase    = (int*)alloc(256);
  int* counts   = (int*)alloc(256);

  prep_k<<<5632, 256, 0, stream>>>(w1, w3, sw1, sw3, w1T,
                                   x, wrt, xb, rec, wts, probs, lsebuf);
  build_k<<<1, 1024, 0, stream>>>(rec, wts, probs, lsebuf, tlist, wlist,
                                  counts, ebase, tiles, out + (size_t)NTOK * 1024);
  gemm1_k<<<dim3(16, MAXTILES + 144), 256, 0, stream>>>(
      xb, w1T, w3T, sw1T, sw3T, hbuf, tlist, counts, ebase, tiles, w2, sw2, w1T);
  gemm2_k<<<dim3(8, MAXTILES), 256, 0, stream>>>(hbuf, w2T, sw2T, ybuf, out,
                                                 tlist, wlist, counts, ebase, tiles);
  combine_k<<<NTOK * 1024 / 4 / 256, 256, 0, stream>>>(ybuf, out);
}

// Round 7
// 295.215 us; speedup vs baseline: 1.2625x; 1.0141x over previous
//
#include <hip/hip_runtime.h>

#define NTOK 4096
#define NEXP 8
#define MAXTILES 104

typedef __attribute__((ext_vector_type(8))) short short8;
typedef __attribute__((ext_vector_type(4))) float f32x4;
typedef __attribute__((ext_vector_type(4))) unsigned int uint4v;
typedef __attribute__((ext_vector_type(2))) unsigned int uint2v;

__device__ __forceinline__ unsigned short f2bf(float f) {
  union { float f; unsigned u; } v; v.f = f;
  unsigned u = v.u;
  return (unsigned short)((u + 0x7FFFu + ((u >> 16) & 1u)) >> 16);
}

__device__ __forceinline__ void gll16(const void* g, void* l) {
  __builtin_amdgcn_global_load_lds((const __attribute__((address_space(1))) void*)g,
                                   (__attribute__((address_space(3))) void*)l, 16, 0, 0);
}

// derive this block's tile from counts[] (R4-proven; replaces tiles/ebase tables)
__device__ __forceinline__ bool tile_lookup(const int* __restrict__ counts, int y,
                                            int& e, int& m0, int& n_e, int& hb) {
  int base = 0, acc = 0;
#pragma unroll
  for (int ee = 0; ee < NEXP; ++ee) {
    int c = counts[ee];
    int nt = (c + 127) >> 7;
    if (y < acc + nt) { e = ee; m0 = (y - acc) << 7; n_e = c; hb = base; return true; }
    acc += nt; base += nt << 7;
  }
  int ys = y - acc;
  if (ys < 32) { e = NEXP; m0 = ys << 7; n_e = NTOK; hb = base; return true; }
  return false;
}

// shared 64x64 fp32->bf16 transpose tile body (proven: 0 bank conflicts)
__device__ __forceinline__ void transpose_tile(const float* __restrict__ S,
                                               unsigned short* __restrict__ Dp,
                                               int r0, int c0, int t,
                                               unsigned short (*tile)[65]) {
  int r = t >> 2, cb = (t & 3) * 16;
  const float* sp = S + (size_t)(r0 + r) * 1024 + c0 + cb;
  f32x4 v0 = ((const f32x4*)sp)[0], v1 = ((const f32x4*)sp)[1];
  f32x4 v2 = ((const f32x4*)sp)[2], v3 = ((const f32x4*)sp)[3];
#pragma unroll
  for (int j = 0; j < 4; ++j) {
    tile[r][cb + j] = f2bf(v0[j]);
    tile[r][cb + 4 + j] = f2bf(v1[j]);
    tile[r][cb + 8 + j] = f2bf(v2[j]);
    tile[r][cb + 12 + j] = f2bf(v3[j]);
  }
  __syncthreads();
  unsigned short* dp = Dp + (size_t)(c0 + r) * 1024 + r0 + cb;
  uint4v o0, o1;
#pragma unroll
  for (int j = 0; j < 4; ++j) {
    o0[j] = (unsigned)tile[cb + 2 * j][r] | ((unsigned)tile[cb + 2 * j + 1][r] << 16);
    o1[j] = (unsigned)tile[cb + 8 + 2 * j][r] | ((unsigned)tile[cb + 9 + 2 * j][r] << 16);
  }
  ((uint4v*)dp)[0] = o0;
  ((uint4v*)dp)[1] = o1;
}

// ---- prep: blocks [0,4608) = w1/w3/sw1/sw3 transpose (18 slices); [4608,5632) = router ----
__global__ __launch_bounds__(256) void prep_k(
    const float* __restrict__ w1, const float* __restrict__ w3,
    const float* __restrict__ sw1, const float* __restrict__ sw3,
    unsigned short* __restrict__ dst /* w1T base */,
    const float* __restrict__ x, const float* __restrict__ wr, unsigned short* __restrict__ xb,
    int* __restrict__ rec, float* __restrict__ wts, float* __restrict__ probs,
    float* __restrict__ lsebuf) {
  __shared__ unsigned short tile[64][65];
  int b = blockIdx.x;
  if (b < 4608) {
    int z = b >> 8, rem = b & 255;
    const float* S;
    unsigned short* Dp;
    if (z < 8) { S = w1 + (size_t)z * 1048576; Dp = dst + (size_t)z * 1048576; }
    else if (z < 16) { S = w3 + (size_t)(z - 8) * 1048576; Dp = dst + (size_t)z * 1048576; }
    else if (z == 16) { S = sw1; Dp = dst + (size_t)24 * 1048576; }
    else { S = sw3; Dp = dst + (size_t)25 * 1048576; }
    transpose_tile(S, Dp, (rem >> 4) * 64, (rem & 15) * 64, threadIdx.x, tile);
  } else {
    int t = threadIdx.x, lane = t & 63, wv = t >> 6;
    int tok = (b - 4608) * 4 + wv;
    const f32x4* x4 = (const f32x4*)(x + (size_t)tok * 1024);
    f32x4 xv[4];
#pragma unroll
    for (int j = 0; j < 4; ++j) xv[j] = x4[j * 64 + lane];

    unsigned short* xo = xb + (size_t)tok * 1024;
#pragma unroll
    for (int j = 0; j < 4; ++j) {
      uint2v o;
      o[0] = (unsigned)f2bf(xv[j][0]) | ((unsigned)f2bf(xv[j][1]) << 16);
      o[1] = (unsigned)f2bf(xv[j][2]) | ((unsigned)f2bf(xv[j][3]) << 16);
      *(uint2v*)(xo + j * 256 + lane * 4) = o;
    }

    float acc[NEXP];
#pragma unroll
    for (int e = 0; e < NEXP; ++e) acc[e] = 0.f;
#pragma unroll
    for (int j = 0; j < 4; ++j) {
      int base = j * 256 + lane * 4;
#pragma unroll
      for (int c = 0; c < 4; ++c) {
        float xf = xv[j][c];
        const f32x4* wp = (const f32x4*)(wr + (size_t)(base + c) * NEXP);
        f32x4 q0 = wp[0], q1 = wp[1];
#pragma unroll
        for (int e = 0; e < 4; ++e) { acc[e] += xf * q0[e]; acc[4 + e] += xf * q1[e]; }
      }
    }
#pragma unroll
    for (int off = 32; off > 0; off >>= 1) {
#pragma unroll
      for (int e = 0; e < NEXP; ++e) acc[e] += __shfl_xor(acc[e], off);
    }

    float mx = acc[0];
#pragma unroll
    for (int e = 1; e < NEXP; ++e) mx = fmaxf(mx, acc[e]);
    float s = 0.f;
#pragma unroll
    for (int e = 0; e < NEXP; ++e) s += __expf(acc[e] - mx);
    float inv = 1.f / s;

    if (lane < NEXP) probs[(size_t)tok * NEXP + lane] = __expf(acc[lane] - mx) * inv;
    if (lane == 0) {
      int i0 = 0; float v0 = acc[0];
#pragma unroll
      for (int e = 1; e < NEXP; ++e) if (acc[e] > v0) { v0 = acc[e]; i0 = e; }
      int i1 = -1; float v1 = -3.4e38f;
#pragma unroll
      for (int e = 0; e < NEXP; ++e) if (e != i0 && acc[e] > v1) { v1 = acc[e]; i1 = e; }
      rec[tok] = i0 | (i1 << 8);
      wts[2 * tok] = __expf(v0 - mx) * inv;
      wts[2 * tok + 1] = __expf(v1 - mx) * inv;
      lsebuf[tok] = mx + __logf(s);
    }
  }
}

// ---- build: 8 parallel blocks (one per expert) — deterministic prefix-scan compaction ----
// replaces single-block LDS-atomic build (R6: ~20-25us serial bubble, 255 CUs idle)
__global__ __launch_bounds__(1024) void build_k(
    const int* __restrict__ rec, const float* __restrict__ wts,
    int* __restrict__ tlist, float* __restrict__ wlist, int* __restrict__ counts) {
  const int e = blockIdx.x;
  const int t = threadIdx.x, lane = t & 63, wv = t >> 6;

  // each thread owns tokens [t*4, t*4+4) — preserves ascending token order
  int myk[4];
  int cnt = 0;
#pragma unroll
  for (int j = 0; j < 4; ++j) {
    int r = rec[t * 4 + j];
    if ((r & 255) == e) { myk[j] = 0; cnt++; }
    else if (((r >> 8) & 255) == e) { myk[j] = 1; cnt++; }
    else myk[j] = -1;
  }

  // inclusive wave scan of cnt
  int v = cnt;
#pragma unroll
  for (int off = 1; off < 64; off <<= 1) {
    int u = __shfl_up(v, off);
    if (lane >= off) v += u;
  }
  __shared__ int wsum[16];
  if (lane == 63) wsum[wv] = v;
  __syncthreads();
  int wbase = 0;
#pragma unroll
  for (int w = 0; w < 16; ++w) wbase += (w < wv) ? wsum[w] : 0;
  int pos = wbase + v - cnt;  // exclusive prefix for this thread

  int* tl = tlist + e * NTOK;
  float* wl = wlist + e * NTOK;
#pragma unroll
  for (int j = 0; j < 4; ++j) {
    if (myk[j] >= 0) {
      int tok = t * 4 + j;
      tl[pos] = tok | (myk[j] << 16);
      wl[pos] = wts[2 * tok + myk[j]];
      ++pos;
    }
  }
  if (t == 0) {
    int tot = 0;
#pragma unroll
    for (int w = 0; w < 16; ++w) tot += wsum[w];
    counts[e] = tot;
  }
}

// ---- GEMM1: y<MAXTILES: 128x64 dual-B SwiGLU tiles; y>=MAXTILES: w2/sw2 transpose ----
// launch_bounds (256,3): proven optimum — 4 blocks/CU thrashes L2 (R2: FETCH 117->205MB, 2x dur)
// chunked XCD swizzle (R5): FETCH -24%, dur neutral (structure-bound, not BW-bound)
__global__ __launch_bounds__(256, 3) void gemm1_k(
    const unsigned short* __restrict__ xb,
    const unsigned short* __restrict__ w1T, const unsigned short* __restrict__ w3T,
    const unsigned short* __restrict__ sw1T, const unsigned short* __restrict__ sw3T,
    unsigned short* __restrict__ hout,
    const int* __restrict__ tlist, const int* __restrict__ counts,
    const float* __restrict__ w2, const float* __restrict__ sw2,
    unsigned short* __restrict__ wTbase /* = w1T; w2T at +16M, sw2T at +26M */) {
  __shared__ unsigned short As[128 * 64], Bs1[64 * 64], Bs3[64 * 64];
  const int tid = threadIdx.x;

  if (blockIdx.y >= MAXTILES) {
    // ---- w2/sw2 transpose: 9 slices x 256 tiles ----
    int tb = (blockIdx.y - MAXTILES) * 16 + blockIdx.x;  // 0..2303
    int z = tb >> 8, rem = tb & 255;
    const float* S = (z < 8) ? w2 + (size_t)z * 1048576 : sw2;
    unsigned short* Dp = (z < 8) ? wTbase + (size_t)(16 + z) * 1048576
                                 : wTbase + (size_t)26 * 1048576;
    transpose_tile(S, Dp, (rem >> 4) * 64, (rem & 15) * 64, tid,
                   (unsigned short (*)[65])As);
    return;
  }

  // XCD-aware chunked swizzle: hw bid%8 = XCD; give each XCD 208 contiguous logical tiles
  int bid = blockIdx.y * 16 + blockIdx.x;
  int swz = (bid & 7) * 208 + (bid >> 3);
  int ty = swz >> 4, tx = swz & 15;

  int e, m0, n_e, hb;
  if (!tile_lookup(counts, ty, e, m0, n_e, hb)) return;
  const int n0 = tx * 64;
  const bool sh = (e == NEXP);
  const unsigned short* B1p = sh ? sw1T : w1T + (size_t)e * 1048576;
  const unsigned short* B3p = sh ? sw3T : w3T + (size_t)e * 1048576;
  const int* listp = tlist + e * NTOK;

  const int lane = tid & 63, wv = tid >> 6;
  const int wrw = wv >> 1, wc = wv & 1, l16 = lane & 15, lq = lane >> 4;

  const unsigned short* ga[4];
#pragma unroll
  for (int i = 0; i < 4; ++i) {
    int c = tid + i * 256;
    int r = c >> 3, ks = (c & 7) ^ (r & 7);
    int ar = m0 + r;
    int rowA = sh ? ar : (ar < n_e ? (listp[ar] & 0xFFFF) : 0);
    ga[i] = xb + (size_t)rowA * 1024 + ks * 8;
  }
  const unsigned short* gb[2];
  const unsigned short* gc[2];
#pragma unroll
  for (int i = 0; i < 2; ++i) {
    int c = tid + i * 256;
    int r = c >> 3, ks = (c & 7) ^ (r & 7);
    gb[i] = B1p + (size_t)(n0 + r) * 1024 + ks * 8;
    gc[i] = B3p + (size_t)(n0 + r) * 1024 + ks * 8;
  }
  unsigned short* lA[4];
#pragma unroll
  for (int i = 0; i < 4; ++i) lA[i] = As + i * 2048 + wv * 512;
  unsigned short* lB[2] = {Bs1 + wv * 512, Bs1 + 2048 + wv * 512};
  unsigned short* lC[2] = {Bs3 + wv * 512, Bs3 + 2048 + wv * 512};

  f32x4 accg[4][2], accu[4][2];
#pragma unroll
  for (int mi = 0; mi < 4; ++mi)
#pragma unroll
    for (int ni = 0; ni < 2; ++ni)
#pragma unroll
      for (int r = 0; r < 4; ++r) { accg[mi][ni][r] = 0.f; accu[mi][ni][r] = 0.f; }

  for (int k0 = 0; k0 < 1024; k0 += 64) {
#pragma unroll
    for (int i = 0; i < 4; ++i) { gll16(ga[i], lA[i]); ga[i] += 64; }
#pragma unroll
    for (int i = 0; i < 2; ++i) { gll16(gb[i], lB[i]); gb[i] += 64; gll16(gc[i], lC[i]); gc[i] += 64; }
    __syncthreads();
#pragma unroll
    for (int kh = 0; kh < 2; ++kh) {
      short8 af[4], b1f[2], b3f[2];
#pragma unroll
      for (int mi = 0; mi < 4; ++mi) {
        int R = wrw * 64 + mi * 16 + l16;
        int s = (kh * 4 + lq) ^ (R & 7);
        af[mi] = *(const short8*)&As[R * 64 + s * 8];
      }
#pragma unroll
      for (int ni = 0; ni < 2; ++ni) {
        int R = wc * 32 + ni * 16 + l16;
        int s = (kh * 4 + lq) ^ (R & 7);
        b1f[ni] = *(const short8*)&Bs1[R * 64 + s * 8];
        b3f[ni] = *(const short8*)&Bs3[R * 64 + s * 8];
      }
#pragma unroll
      for (int mi = 0; mi < 4; ++mi)
#pragma unroll
        for (int ni = 0; ni < 2; ++ni) {
          accg[mi][ni] = __builtin_amdgcn_mfma_f32_16x16x32_bf16(af[mi], b1f[ni], accg[mi][ni], 0, 0, 0);
          accu[mi][ni] = __builtin_amdgcn_mfma_f32_16x16x32_bf16(af[mi], b3f[ni], accu[mi][ni], 0, 0, 0);
        }
    }
    __syncthreads();
  }

#pragma unroll
  for (int mi = 0; mi < 4; ++mi)
#pragma unroll
    for (int ni = 0; ni < 2; ++ni) {
      int col = n0 + wc * 32 + ni * 16 + l16;
#pragma unroll
      for (int r = 0; r < 4; ++r) {
        int row = m0 + wrw * 64 + mi * 16 + lq * 4 + r;
        float g = accg[mi][ni][r], u = accu[mi][ni][r];
        float h = g / (1.f + __expf(-g)) * u;
        hout[(size_t)(hb + row) * 1024 + col] = (row < n_e) ? f2bf(h) : (unsigned short)0;
      }
    }
}

// ---- GEMM2: 128x128 tile, BK=64; expert tiles -> ybuf[k] slices, shared -> out ----
__global__ __launch_bounds__(256, 3) void gemm2_k(
    const unsigned short* __restrict__ hbuf,
    const unsigned short* __restrict__ w2T, const unsigned short* __restrict__ sw2T,
    float* __restrict__ ybuf, float* __restrict__ out,
    const int* __restrict__ tlist, const float* __restrict__ wlist,
    const int* __restrict__ counts) {
  // XCD-aware chunked swizzle (grid 8x104 = 832 = 8*104, bijective)
  int bid = blockIdx.y * 8 + blockIdx.x;
  int swz = (bid & 7) * 104 + (bid >> 3);
  int ty = swz >> 3, tx = swz & 7;

  int e, m0, n_e, hb;
  if (!tile_lookup(counts, ty, e, m0, n_e, hb)) return;
  const int n0 = tx * 128;
  const bool sh = (e == NEXP);
  const unsigned short* Bp = sh ? sw2T : w2T + (size_t)e * 1048576;
  const int* listp = tlist + e * NTOK;

  __shared__ unsigned short As[128 * 64], Bs[128 * 64];
  const int tid = threadIdx.x, lane = tid & 63, wv = tid >> 6;
  const int wrw = wv >> 1, wc = wv & 1, l16 = lane & 15, lq = lane >> 4;

  const unsigned short* ga[4];
#pragma unroll
  for (int i = 0; i < 4; ++i) {
    int c = tid + i * 256;
    int r = c >> 3, ks = (c & 7) ^ (r & 7);
    ga[i] = hbuf + (size_t)(hb + m0 + r) * 1024 + ks * 8;  // padded rows zero-filled
  }
  const unsigned short* gb[4];
#pragma unroll
  for (int i = 0; i < 4; ++i) {
    int c = tid + i * 256;
    int r = c >> 3, ks = (c & 7) ^ (r & 7);
    gb[i] = Bp + (size_t)(n0 + r) * 1024 + ks * 8;
  }
  unsigned short* lA[4];
  unsigned short* lB[4];
#pragma unroll
  for (int i = 0; i < 4; ++i) {
    lA[i] = As + i * 2048 + wv * 512;
    lB[i] = Bs + i * 2048 + wv * 512;
  }

  f32x4 acc[4][4];
#pragma unroll
  for (int mi = 0; mi < 4; ++mi)
#pragma unroll
    for (int ni = 0; ni < 4; ++ni)
#pragma unroll
      for (int r = 0; r < 4; ++r) acc[mi][ni][r] = 0.f;

  for (int k0 = 0; k0 < 1024; k0 += 64) {
#pragma unroll
    for (int i = 0; i < 4; ++i) { gll16(ga[i], lA[i]); ga[i] += 64; gll16(gb[i], lB[i]); gb[i] += 64; }
    __syncthreads();
#pragma unroll
    for (int kh = 0; kh < 2; ++kh) {
      short8 af[4], bf[4];
#pragma unroll
      for (int mi = 0; mi < 4; ++mi) {
        int R = wrw * 64 + mi * 16 + l16;
        int s = (kh * 4 + lq) ^ (R & 7);
        af[mi] = *(const short8*)&As[R * 64 + s * 8];
      }
#pragma unroll
      for (int ni = 0; ni < 4; ++ni) {
        int R = wc * 64 + ni * 16 + l16;
        int s = (kh * 4 + lq) ^ (R & 7);
        bf[ni] = *(const short8*)&Bs[R * 64 + s * 8];
      }
#pragma unroll
      for (int mi = 0; mi < 4; ++mi)
#pragma unroll
        for (int ni = 0; ni < 4; ++ni)
          acc[mi][ni] = __builtin_amdgcn_mfma_f32_16x16x32_bf16(af[mi], bf[ni], acc[mi][ni], 0, 0, 0);
    }
    __syncthreads();
  }

#pragma unroll
  for (int mi = 0; mi < 4; ++mi)
#pragma unroll
    for (int r = 0; r < 4; ++r) {
      int row = m0 + wrw * 64 + mi * 16 + lq * 4 + r;
      if (sh) {
        float* yp = out + (size_t)row * 1024 + n0 + wc * 64 + l16;
#pragma unroll
        for (int ni = 0; ni < 4; ++ni) yp[ni * 16] = acc[mi][ni][r] * (1.f / 3.f);
      } else if (row < n_e) {
        int ent = listp[row];
        float wt = wlist[e * NTOK + row] * (2.f / 3.f);
        int tok = ent & 0xFFFF, ks = ent >> 16;
        float* yp = ybuf + ((size_t)ks * NTOK + tok) * 1024 + n0 + wc * 64 + l16;
#pragma unroll
        for (int ni = 0; ni < 4; ++ni) yp[ni * 16] = wt * acc[mi][ni][r];
      }
    }
}

// ---- combine: blocks [0,4096): out += y0 + y1; block 4096: loss reduction ----
__global__ __launch_bounds__(256) void combine_k(const float* __restrict__ y,
                                                 float* __restrict__ out,
                                                 const float* __restrict__ probs,
                                                 const float* __restrict__ lsebuf,
                                                 const int* __restrict__ counts,
                                                 float* __restrict__ lossout) {
  if (blockIdx.x < NTOK * 1024 / 4 / 256) {
    size_t i = (size_t)blockIdx.x * 256 + threadIdx.x;
    const f32x4* y0 = (const f32x4*)y + i;
    const f32x4* y1 = y0 + (NTOK * 1024 / 4);
    f32x4 o = ((f32x4*)out)[i];
    ((f32x4*)out)[i] = o + *y0 + *y1;
    return;
  }
  // loss block (R4-proven): reads only prep/build outputs
  int t = threadIdx.x, lane = t & 63, wv = t >> 6;
  float pacc[NEXP];
#pragma unroll
  for (int e = 0; e < NEXP; ++e) pacc[e] = 0.f;
  float zacc = 0.f;
#pragma unroll
  for (int it = 0; it < 16; ++it) {
    int tok = t + it * 256;
    f32x4 a = ((const f32x4*)(probs + (size_t)tok * NEXP))[0];
    f32x4 c = ((const f32x4*)(probs + (size_t)tok * NEXP))[1];
#pragma unroll
    for (int j = 0; j < 4; ++j) { pacc[j] += a[j]; pacc[4 + j] += c[j]; }
    float lv = lsebuf[tok];
    zacc += lv * lv;
  }
#pragma unroll
  for (int off = 32; off > 0; off >>= 1) {
#pragma unroll
    for (int e = 0; e < NEXP; ++e) pacc[e] += __shfl_xor(pacc[e], off);
    zacc += __shfl_xor(zacc, off);
  }
  __shared__ float red[4][NEXP + 1];
  if (lane == 0) {
#pragma unroll
    for (int e = 0; e < NEXP; ++e) red[wv][e] = pacc[e];
    red[wv][NEXP] = zacc;
  }
  __syncthreads();
  if (t == 0) {
    float dot = 0.f, z = 0.f;
    for (int e = 0; e < NEXP; ++e) {
      float se = red[0][e] + red[1][e] + red[2][e] + red[3][e];
      dot += (float)counts[e] * se;
    }
    z = red[0][NEXP] + red[1][NEXP] + red[2][NEXP] + red[3][NEXP];
    lossout[0] = 6.103515625e-7f * dot;  // E*LB_W/(NUM_LAYERS*N*K)
    lossout[1] = z * (0.001f / 4096.f);
  }
}

extern "C" void kernel_launch(void* const* d_in, const int* in_sizes, int n_in,
                              void* d_out, int out_size, void* d_ws, size_t ws_size,
                              hipStream_t stream) {
  const float* x   = (const float*)d_in[0];
  const float* wrt = (const float*)d_in[1];
  const float* w1  = (const float*)d_in[2];
  const float* w3  = (const float*)d_in[3];
  const float* w2  = (const float*)d_in[4];
  const float* sw1 = (const float*)d_in[5];
  const float* sw3 = (const float*)d_in[6];
  const float* sw2 = (const float*)d_in[7];
  float* out = (float*)d_out;

  char* p = (char*)d_ws;
  auto alloc = [&](size_t b) { char* r = p; p += (b + 255) & ~(size_t)255; return r; };
  unsigned short* xb   = (unsigned short*)alloc((size_t)NTOK * 1024 * 2);
  // contiguous: w1T(8) w3T(8) w2T(8) sw1T sw3T sw2T = 27 x 1M elems
  unsigned short* w1T  = (unsigned short*)alloc((size_t)27 * 1048576 * 2);
  unsigned short* w3T  = w1T + (size_t)8 * 1048576;
  unsigned short* w2T  = w3T + (size_t)8 * 1048576;
  unsigned short* sw1T = w2T + (size_t)8 * 1048576;
  unsigned short* sw3T = sw1T + 1048576;
  unsigned short* sw2T = sw3T + 1048576;
  unsigned short* hbuf = (unsigned short*)alloc((size_t)13312 * 1024 * 2);
  float* ybuf   = (float*)alloc((size_t)2 * NTOK * 1024 * 4);
  int* tlist    = (int*)alloc((size_t)NEXP * NTOK * 4);
  float* wlist  = (float*)alloc((size_t)NEXP * NTOK * 4);
  int* rec      = (int*)alloc((size_t)NTOK * 4);
  float* wts    = (float*)alloc((size_t)NTOK * 2 * 4);
  float* probs  = (float*)alloc((size_t)NTOK * NEXP * 4);
  float* lsebuf = (float*)alloc((size_t)NTOK * 4);
  int* counts   = (int*)alloc(256);

  prep_k<<<5632, 256, 0, stream>>>(w1, w3, sw1, sw3, w1T,
                                   x, wrt, xb, rec, wts, probs, lsebuf);
  build_k<<<NEXP, 1024, 0, stream>>>(rec, wts, tlist, wlist, counts);
  gemm1_k<<<dim3(16, MAXTILES + 144), 256, 0, stream>>>(
      xb, w1T, w3T, sw1T, sw3T, hbuf, tlist, counts, w2, sw2, w1T);
  gemm2_k<<<dim3(8, MAXTILES), 256, 0, stream>>>(hbuf, w2T, sw2T, ybuf, out,
                                                 tlist, wlist, counts);
  combine_k<<<NTOK * 1024 / 4 / 256 + 1, 256, 0, stream>>>(
      ybuf, out, probs, lsebuf, counts, out + (size_t)NTOK * 1024);
}